// Round 4
// baseline (9500.262 us; speedup 1.0000x reference)
//
#include <hip/hip_runtime.h>
#include <hip/hip_bf16.h>
#include <cstddef>

#define T_SEQ 2048
#define BATCH 64
#define H 128
#define EPS 1e-5f

typedef _Float16 half8_t __attribute__((ext_vector_type(8)));
typedef _Float16 half4_t __attribute__((ext_vector_type(4)));
typedef float floatx4 __attribute__((ext_vector_type(4)));

// ---------- math helpers ----------
__device__ __forceinline__ float sigmoid_f(float x) {
    return __builtin_amdgcn_rcpf(1.0f + __expf(-x));   // rcp(inf)=0 saturates
}
__device__ __forceinline__ float tanh_f(float x) {
    return fmaf(2.0f, __builtin_amdgcn_rcpf(1.0f + __expf(-2.0f * x)), -1.0f);
}
__device__ __forceinline__ float mish_f(float x) {
    float sp = (x > 15.0f) ? x : log1pf(__expf(x));
    return x * tanh_f(sp);
}

// ---------- input-projection GEMM ----------
// C[(t*B+b)][col] = A[(b*T+t)][:K] . W[col][:K] + bih[col] + (col<256 ? bhh[col] : 0)
// (bhh folded for r,z gates; n-gate's bhh must stay separate for r*(hn+bhn))
template<int K>
__global__ __launch_bounds__(256, 2)
void proj_kernel(const float* __restrict__ A, const float* __restrict__ W,
                 const float* __restrict__ bih, const float* __restrict__ bhh,
                 float* __restrict__ C)
{
    __shared__ float As[16][128];
    __shared__ float Ws[16][128];
    const int n0 = blockIdx.x * 128;
    const int m0 = blockIdx.y * 128;
    const int tid = threadIdx.x;
    const int tx = tid & 15;
    const int ty = tid >> 4;
    float acc[8][8];
    #pragma unroll
    for (int i = 0; i < 8; ++i)
        #pragma unroll
        for (int j = 0; j < 8; ++j) acc[i][j] = 0.0f;

    for (int k0 = 0; k0 < K; k0 += 16) {
        #pragma unroll
        for (int i = 0; i < 2; ++i) {
            const int f = tid + i * 256;
            const int r = f >> 2;
            const int kq = (f & 3) << 2;
            const int m = m0 + r;
            const size_t arow = (size_t)(m & 63) * T_SEQ + (m >> 6); // b*T+t
            const float4 av = *reinterpret_cast<const float4*>(&A[arow * K + k0 + kq]);
            As[kq + 0][r] = av.x; As[kq + 1][r] = av.y;
            As[kq + 2][r] = av.z; As[kq + 3][r] = av.w;
            const float4 wv = *reinterpret_cast<const float4*>(&W[(size_t)(n0 + r) * K + k0 + kq]);
            Ws[kq + 0][r] = wv.x; Ws[kq + 1][r] = wv.y;
            Ws[kq + 2][r] = wv.z; Ws[kq + 3][r] = wv.w;
        }
        __syncthreads();
        #pragma unroll
        for (int kk = 0; kk < 16; ++kk) {
            float a[8], b[8];
            *reinterpret_cast<float4*>(&a[0]) = *reinterpret_cast<const float4*>(&As[kk][ty * 8]);
            *reinterpret_cast<float4*>(&a[4]) = *reinterpret_cast<const float4*>(&As[kk][ty * 8 + 4]);
            *reinterpret_cast<float4*>(&b[0]) = *reinterpret_cast<const float4*>(&Ws[kk][tx * 8]);
            *reinterpret_cast<float4*>(&b[4]) = *reinterpret_cast<const float4*>(&Ws[kk][tx * 8 + 4]);
            #pragma unroll
            for (int i = 0; i < 8; ++i)
                #pragma unroll
                for (int j = 0; j < 8; ++j)
                    acc[i][j] = fmaf(a[i], b[j], acc[i][j]);
        }
        __syncthreads();
    }
    float bv[8];
    #pragma unroll
    for (int j = 0; j < 8; ++j) {
        const int col = n0 + tx * 8 + j;
        bv[j] = bih[col] + ((col < 256) ? bhh[col] : 0.0f);
    }
    #pragma unroll
    for (int i = 0; i < 8; ++i) {
        const int m = m0 + ty * 8 + i;
        float* crow = &C[(size_t)m * 384 + n0 + tx * 8];
        float4 o0, o1;
        o0.x = acc[i][0] + bv[0]; o0.y = acc[i][1] + bv[1];
        o0.z = acc[i][2] + bv[2]; o0.w = acc[i][3] + bv[3];
        o1.x = acc[i][4] + bv[4]; o1.y = acc[i][5] + bv[5];
        o1.z = acc[i][6] + bv[6]; o1.w = acc[i][7] + bv[7];
        *reinterpret_cast<float4*>(&crow[0]) = o0;
        *reinterpret_cast<float4*>(&crow[4]) = o1;
    }
}

// ---------- MFMA GRU scan v3 ----------
// 512 threads = 8 waves = TWO independent 4-wave chains (16 batches each).
// Chain wave wc owns 6 M-tiles {g*8 + jj*4 + wc} of [384x128] Whh (fp16
// A-frags, 96 VGPR). Per step: 24 mfma_16x16x32_f16 into 6 fp32 accs seeded
// with xp (r,z) / bhh_n (n) -- the D layout (col=lane&15,row=(lane>>4)*4+rr)
// matches the xp register layout, so no cross-lane motion for gates.
// h exchanged via XOR-swizzled double-buffered LDS (one lgkm-only barrier
// per step). xp prefetch: pure-SSA double-buffered register sets -- macro
// role-swap, ZERO copies, so the compiler emits counted vmcnt waits.
__device__ __forceinline__ int hoff(int n, int k) {
    return (n * 256 + k * 2) ^ ((n & 7) << 4);
}
#define LDS_BARRIER() asm volatile("s_waitcnt lgkmcnt(0)\n\ts_barrier" ::: "memory")

__global__ __launch_bounds__(512, 1)
void gru_scan4(const float* __restrict__ xpA, const float* __restrict__ xpB,
               const float* __restrict__ WA, const float* __restrict__ WB,
               const float* __restrict__ bA, const float* __restrict__ bB,
               int revA, int revB,
               float* __restrict__ seqout,   // x1 [B][T][256] or nullptr
               float* __restrict__ hfin)     // [B][H] or nullptr
{
    const int tid = threadIdx.x;
    const int w = tid >> 6;        // wave 0..7
    const int l = tid & 63;
    const int n = l & 15;          // batch slot
    const int q = l >> 4;          // lane quarter
    const int ch = w >> 2;         // chain slot in block (0/1)
    const int wc = w & 3;          // wave within chain

    const int c = blockIdx.x * 2 + ch;   // global chain id
    const int dir = c >> 2;
    const int g0 = (c & 3) * 16;

    const float* __restrict__ xp  = dir ? xpB : xpA;
    const float* __restrict__ Whh = dir ? WB : WA;
    const float* __restrict__ bhh = dir ? bB : bA;
    const int rev = dir ? revB : revA;

    __shared__ __align__(16) unsigned char hlds[2][2][4096];

    {   // zero h buffer 0 of both chains (512 thr x 16B = 8KB)
        const int zch = tid >> 8, zo = (tid & 255) * 16;
        *reinterpret_cast<floatx4*>(&hlds[zch][0][zo]) = floatx4{0.f, 0.f, 0.f, 0.f};
    }

    // Whh fragments -> fp16, resident (96 VGPR)
    half8_t wf[6][4];
    #pragma unroll
    for (int g = 0; g < 3; ++g)
        #pragma unroll
        for (int jj = 0; jj < 2; ++jj) {
            const int row = g * 128 + jj * 64 + wc * 16 + n;
            const float* wr = &Whh[(size_t)row * 128 + q * 8];
            #pragma unroll
            for (int kt = 0; kt < 4; ++kt) {
                half8_t hf;
                #pragma unroll
                for (int e = 0; e < 8; ++e) hf[e] = (_Float16)wr[kt * 32 + e];
                wf[g * 2 + jj][kt] = hf;
            }
        }

    const int batch = g0 + n;
    floatx4 bN[2];
    bN[0] = *reinterpret_cast<const floatx4*>(&bhh[256 + wc * 16 + q * 4]);
    bN[1] = *reinterpret_cast<const floatx4*>(&bhh[256 + 64 + wc * 16 + q * 4]);

    floatx4 hp[2] = {{0.f,0.f,0.f,0.f}, {0.f,0.f,0.f,0.f}};

    int t = rev ? (T_SEQ - 1) : 0;
    const int ts = rev ? -1 : 1;

    // lane-constant xp base: xp[(t*64 + batch)*384 + col], col(i) = (i>>1)*128 + (i&1)*64 + wc*16 + q*4
    const float* xlane = xp + (size_t)batch * 384 + wc * 16 + q * 4;

    floatx4 XA[6], XB[6];
    #pragma unroll
    for (int i = 0; i < 6; ++i)
        XA[i] = *reinterpret_cast<const floatx4*>(
            xlane + (size_t)t * 24576 + (i >> 1) * 128 + (i & 1) * 64);

    __syncthreads();   // h-init + first xp visible

#define GRU_STEP(RB, WB_, XC, XN_, TCUR, TNXT)                                      \
    do {                                                                            \
        /* issue next-step xp loads into the OTHER register set (no copies) */      \
        _Pragma("unroll")                                                           \
        for (int i = 0; i < 6; ++i)                                                 \
            XN_[i] = *reinterpret_cast<const floatx4*>(                             \
                xlane + (size_t)(TNXT) * 24576 + (i >> 1) * 128 + (i & 1) * 64);    \
        half8_t bf[4];                                                              \
        _Pragma("unroll")                                                           \
        for (int kt = 0; kt < 4; ++kt)                                              \
            bf[kt] = *reinterpret_cast<const half8_t*>(                             \
                &hlds[ch][RB][hoff(n, kt * 32 + q * 8)]);                           \
        floatx4 a[6];                                                               \
        a[0] = XC[0]; a[1] = XC[1]; a[2] = XC[2]; a[3] = XC[3];                     \
        a[4] = bN[0]; a[5] = bN[1];                                                 \
        _Pragma("unroll")                                                           \
        for (int kt = 0; kt < 4; ++kt)                                              \
            _Pragma("unroll")                                                       \
            for (int i = 0; i < 6; ++i)                                             \
                a[i] = __builtin_amdgcn_mfma_f32_16x16x32_f16(wf[i][kt], bf[kt], a[i], 0, 0, 0); \
        _Pragma("unroll")                                                           \
        for (int jj = 0; jj < 2; ++jj) {                                            \
            floatx4 hnew;                                                           \
            half4_t hh;                                                             \
            _Pragma("unroll")                                                       \
            for (int rr = 0; rr < 4; ++rr) {                                        \
                const float rg = sigmoid_f(a[jj][rr]);                              \
                const float zg = sigmoid_f(a[2 + jj][rr]);                          \
                const float nn = tanh_f(XC[4 + jj][rr] + rg * a[4 + jj][rr]);       \
                const float hv = fmaf(zg, hp[jj][rr] - nn, nn);                     \
                hnew[rr] = hv;                                                      \
                hh[rr] = (_Float16)hv;                                              \
            }                                                                       \
            hp[jj] = hnew;                                                          \
            *reinterpret_cast<half4_t*>(                                            \
                &hlds[ch][WB_][hoff(n, jj * 64 + wc * 16 + q * 4)]) = hh;           \
            if (seqout)                                                             \
                *reinterpret_cast<floatx4*>(                                        \
                    &seqout[((size_t)batch * T_SEQ + (TCUR)) * 256 + dir * 128 +    \
                            jj * 64 + wc * 16 + q * 4]) = hnew;                     \
        }                                                                           \
        LDS_BARRIER();                                                              \
    } while (0)

    for (int s = 0; s < T_SEQ; s += 2) {
        const int t0 = t;
        const int t1 = t + ts;
        int t2 = t + 2 * ts;
        t2 = (t2 < 0) ? 0 : ((t2 > T_SEQ - 1) ? T_SEQ - 1 : t2);
        GRU_STEP(0, 1, XA, XB, t0, t1);   // consume A (holds t0), load B <- t1
        GRU_STEP(1, 0, XB, XA, t1, t2);   // consume B (holds t1), load A <- t2
        t += 2 * ts;
    }
#undef GRU_STEP

    if (hfin) {
        *reinterpret_cast<floatx4*>(&hfin[(size_t)batch * 128 + wc * 16 + q * 4]) = hp[0];
        *reinterpret_cast<floatx4*>(&hfin[(size_t)batch * 128 + 64 + wc * 16 + q * 4]) = hp[1];
    }
}

// ---------- decoder ----------
__device__ __forceinline__ float block_sum128(float v, float* red) {
    #pragma unroll
    for (int o = 32; o > 0; o >>= 1) v += __shfl_down(v, o);
    const int w = threadIdx.x >> 6;
    if ((threadIdx.x & 63) == 0) red[w] = v;
    __syncthreads();
    const float s = red[0] + red[1];
    __syncthreads();
    return s;
}

__global__ __launch_bounds__(128, 1)
void decoder_kernel(const float* __restrict__ hb,
                    const float* __restrict__ g1, const float* __restrict__ be1,
                    const float* __restrict__ W1, const float* __restrict__ b1,
                    const float* __restrict__ g2, const float* __restrict__ be2,
                    const float* __restrict__ W2, const float* __restrict__ b2,
                    float* __restrict__ out)
{
    const int b = blockIdx.x;
    const int j = threadIdx.x;
    __shared__ float buf[H];
    __shared__ float red[2];

    const float m = mish_f(hb[(size_t)b * H + j]);
    const float mean = block_sum128(m, red) * (1.0f / H);
    const float d = m - mean;
    const float var = block_sum128(d * d, red) * (1.0f / H);
    const float y = d * rsqrtf(var + EPS) * g1[j] + be1[j];
    buf[j] = y;
    __syncthreads();

    float acc = b1[j];
    #pragma unroll
    for (int k = 0; k < H; k += 4) {
        const float4 wv = *reinterpret_cast<const float4*>(&W1[(size_t)j * H + k]);
        const float4 yv = *reinterpret_cast<const float4*>(&buf[k]);
        acc += wv.x * yv.x + wv.y * yv.y + wv.z * yv.z + wv.w * yv.w;
    }
    const float m2 = mish_f(acc);
    const float mean2 = block_sum128(m2, red) * (1.0f / H);
    const float d2 = m2 - mean2;
    const float var2 = block_sum128(d2 * d2, red) * (1.0f / H);
    const float y2 = d2 * rsqrtf(var2 + EPS) * g2[j] + be2[j];

    const float p = W2[j] * y2;
    const float s = block_sum128(p, red);
    if (j == 0) out[b] = s + b2[0];
}

// ---------- launch ----------
extern "C" void kernel_launch(void* const* d_in, const int* in_sizes, int n_in,
                              void* d_out, int out_size, void* d_ws, size_t ws_size,
                              hipStream_t stream)
{
    (void)in_sizes; (void)n_in; (void)out_size; (void)ws_size;
    const float* x     = (const float*)d_in[0];
    const float* Wih0f = (const float*)d_in[1];
    const float* Whh0f = (const float*)d_in[2];
    const float* bih0f = (const float*)d_in[3];
    const float* bhh0f = (const float*)d_in[4];
    const float* Wih0b = (const float*)d_in[5];
    const float* Whh0b = (const float*)d_in[6];
    const float* bih0b = (const float*)d_in[7];
    const float* bhh0b = (const float*)d_in[8];
    // d_in[9..12] = layer-1 forward params: unused (hf discarded by reference)
    const float* Wih1b = (const float*)d_in[13];
    const float* Whh1b = (const float*)d_in[14];
    const float* bih1b = (const float*)d_in[15];
    const float* bhh1b = (const float*)d_in[16];
    const float* g1  = (const float*)d_in[17];
    const float* be1 = (const float*)d_in[18];
    const float* W1  = (const float*)d_in[19];
    const float* b1  = (const float*)d_in[20];
    const float* g2  = (const float*)d_in[21];
    const float* be2 = (const float*)d_in[22];
    const float* W2  = (const float*)d_in[23];
    const float* b2  = (const float*)d_in[24];
    float* out = (float*)d_out;

    float* ws = (float*)d_ws;
    const size_t XP_ELEMS = (size_t)T_SEQ * BATCH * 384;
    const size_t X1_ELEMS = (size_t)BATCH * T_SEQ * 256;
    float* xp0f = ws;
    float* xp0b = xp0f + XP_ELEMS;
    float* x1   = xp0b + XP_ELEMS;
    float* hbuf = x1 + X1_ELEMS;
    float* xp1b = xp0f;   // xp0f dead after layer-0 scan

    const dim3 pgrid(3, 1024);
    proj_kernel<512><<<pgrid, 256, 0, stream>>>(x, Wih0f, bih0f, bhh0f, xp0f);
    proj_kernel<512><<<pgrid, 256, 0, stream>>>(x, Wih0b, bih0b, bhh0b, xp0b);
    gru_scan4<<<dim3(4), 512, 0, stream>>>(xp0f, xp0b, Whh0f, Whh0b, bhh0f, bhh0b,
                                           0, 1, x1, nullptr);
    proj_kernel<256><<<pgrid, 256, 0, stream>>>(x1, Wih1b, bih1b, bhh1b, xp1b);
    gru_scan4<<<dim3(2), 512, 0, stream>>>(xp1b, xp1b, Whh1b, Whh1b, bhh1b, bhh1b,
                                           1, 1, nullptr, hbuf);
    decoder_kernel<<<64, 128, 0, stream>>>(hbuf, g1, be1, W1, b1, g2, be2, W2, b2, out);
}

// Round 8
// 4896.067 us; speedup vs baseline: 1.9404x; 1.9404x over previous
//
#include <hip/hip_runtime.h>
#include <hip/hip_bf16.h>
#include <cstddef>

#define T_SEQ 2048
#define BATCH 64
#define H 128
#define EPS 1e-5f

typedef _Float16 half8_t __attribute__((ext_vector_type(8)));
typedef _Float16 half4_t __attribute__((ext_vector_type(4)));
typedef float floatx4 __attribute__((ext_vector_type(4)));

// ---------- math helpers ----------
__device__ __forceinline__ float sigmoid_f(float x) {
    return __builtin_amdgcn_rcpf(1.0f + __expf(-x));   // rcp(inf)=0 saturates
}
__device__ __forceinline__ float tanh_f(float x) {
    return fmaf(2.0f, __builtin_amdgcn_rcpf(1.0f + __expf(-2.0f * x)), -1.0f);
}
__device__ __forceinline__ float mish_f(float x) {
    float sp = (x > 15.0f) ? x : log1pf(__expf(x));
    return x * tanh_f(sp);
}

// ---------- xp layout ----------
// XP[t][g][cq][n][c] : t in [0,2048), g = b>>4 (batch group), cq = col>>2
// (col in [0,384)), n = b&15, c = col&3. Flat = (((t*4+g)*96 + cq)*16 + n)*4 + c.
// A scan wave's per-fragment load (16 lanes x 16B, q blocks of 256B) is 1024B
// fully contiguous; one chain-step = one dense 24KB block.

// ---------- input-projection GEMM ----------
// out[t,b,col] = A[(b*T+t)][:K] . W[col][:K] + bih[col] + (col<256 ? bhh[col] : 0)
// written in the XP layout above. (bhh folded for r,z; n-gate bhh stays
// separate for the r*(hn+bhn) term.)
template<int K>
__global__ __launch_bounds__(256, 2)
void proj_kernel(const float* __restrict__ A, const float* __restrict__ W,
                 const float* __restrict__ bih, const float* __restrict__ bhh,
                 float* __restrict__ C)
{
    __shared__ float As[16][128];
    __shared__ float Ws[16][128];
    const int n0 = blockIdx.x * 128;
    const int m0 = blockIdx.y * 128;
    const int tid = threadIdx.x;
    const int tx = tid & 15;
    const int ty = tid >> 4;
    float acc[8][8];
    #pragma unroll
    for (int i = 0; i < 8; ++i)
        #pragma unroll
        for (int j = 0; j < 8; ++j) acc[i][j] = 0.0f;

    for (int k0 = 0; k0 < K; k0 += 16) {
        #pragma unroll
        for (int i = 0; i < 2; ++i) {
            const int f = tid + i * 256;
            const int r = f >> 2;
            const int kq = (f & 3) << 2;
            const int m = m0 + r;
            const size_t arow = (size_t)(m & 63) * T_SEQ + (m >> 6); // b*T+t
            const float4 av = *reinterpret_cast<const float4*>(&A[arow * K + k0 + kq]);
            As[kq + 0][r] = av.x; As[kq + 1][r] = av.y;
            As[kq + 2][r] = av.z; As[kq + 3][r] = av.w;
            const float4 wv = *reinterpret_cast<const float4*>(&W[(size_t)(n0 + r) * K + k0 + kq]);
            Ws[kq + 0][r] = wv.x; Ws[kq + 1][r] = wv.y;
            Ws[kq + 2][r] = wv.z; Ws[kq + 3][r] = wv.w;
        }
        __syncthreads();
        #pragma unroll
        for (int kk = 0; kk < 16; ++kk) {
            float a[8], b[8];
            *reinterpret_cast<float4*>(&a[0]) = *reinterpret_cast<const float4*>(&As[kk][ty * 8]);
            *reinterpret_cast<float4*>(&a[4]) = *reinterpret_cast<const float4*>(&As[kk][ty * 8 + 4]);
            *reinterpret_cast<float4*>(&b[0]) = *reinterpret_cast<const float4*>(&Ws[kk][tx * 8]);
            *reinterpret_cast<float4*>(&b[4]) = *reinterpret_cast<const float4*>(&Ws[kk][tx * 8 + 4]);
            #pragma unroll
            for (int i = 0; i < 8; ++i)
                #pragma unroll
                for (int j = 0; j < 8; ++j)
                    acc[i][j] = fmaf(a[i], b[j], acc[i][j]);
        }
        __syncthreads();
    }
    float bv[8];
    #pragma unroll
    for (int j = 0; j < 8; ++j) {
        const int col = n0 + tx * 8 + j;
        bv[j] = bih[col] + ((col < 256) ? bhh[col] : 0.0f);
    }
    const int cq0 = (n0 >> 2) + tx * 2;   // first col-quad this thread writes
    #pragma unroll
    for (int i = 0; i < 8; ++i) {
        const int m = m0 + ty * 8 + i;
        const int t = m >> 6, b = m & 63;
        const int gi = b >> 4, ni = b & 15;
        float* base = &C[(((size_t)t * 4 + gi) * 96 + cq0) * 64 + ni * 4];
        float4 o0, o1;
        o0.x = acc[i][0] + bv[0]; o0.y = acc[i][1] + bv[1];
        o0.z = acc[i][2] + bv[2]; o0.w = acc[i][3] + bv[3];
        o1.x = acc[i][4] + bv[4]; o1.y = acc[i][5] + bv[5];
        o1.z = acc[i][6] + bv[6]; o1.w = acc[i][7] + bv[7];
        *reinterpret_cast<float4*>(base) = o0;        // col-quad cq0
        *reinterpret_cast<float4*>(base + 64) = o1;   // col-quad cq0+1
    }
}

// ---------- MFMA GRU scan v5 (r3 shape + 3-deep SSA prefetch + dense xp) ----
// One chain (16 batches, one direction) per block. 512 threads = 8 waves.
// Wave w owns M-tiles {w, 8+w, 16+w} of [384x128] Whh (fp16 A-frags, VGPRs).
// Per step: 12 mfma_16x16x32_f16 into 3 accs seeded {0, 0, bhh_n} (register
// constants -- no vmem dep at MFMA issue). xp consumed LATE (gate phase),
// prefetched 3 steps ahead into 4 rotating named register sets (pure SSA,
// zero copies -> compiler emits counted vmcnt at use). h exchanged via
// XOR-swizzled double-buffered LDS, ONE lgkm-only barrier per step.
__device__ __forceinline__ int hoff(int n, int k) {
    return (n * 256 + k * 2) ^ ((n & 7) << 4);
}
#define LDS_BARRIER() asm volatile("s_waitcnt lgkmcnt(0)\n\ts_barrier" ::: "memory")

__global__ __launch_bounds__(512, 2)
void gru_scan8(const float* __restrict__ xpA, const float* __restrict__ xpB,
               const float* __restrict__ WA, const float* __restrict__ WB,
               const float* __restrict__ bA, const float* __restrict__ bB,
               int revA, int revB,
               float* __restrict__ seqout,   // x1 [B][T][256] or nullptr
               float* __restrict__ hfin)     // [B][H] or nullptr
{
    const int tid = threadIdx.x;
    const int w = tid >> 6;        // wave 0..7
    const int l = tid & 63;
    const int n = l & 15;          // batch slot
    const int q = l >> 4;          // lane quarter

    const int cid = blockIdx.x;
    const int dir = cid >> 2;
    const int g = cid & 3;

    const float* __restrict__ xp  = dir ? xpB : xpA;
    const float* __restrict__ Whh = dir ? WB : WA;
    const float* __restrict__ bhh = dir ? bB : bA;
    const int rev = dir ? revB : revA;

    __shared__ __align__(16) unsigned char hlds[2][4096];

    // zero h buffer 0 (512 thr x 8B)
    *reinterpret_cast<unsigned long long*>(&hlds[0][tid * 8]) = 0ull;

    // Whh fragments -> fp16, resident
    half8_t wf[3][4];
    #pragma unroll
    for (int mi = 0; mi < 3; ++mi) {
        const float* wr = &Whh[(size_t)((mi * 8 + w) * 16 + n) * 128 + q * 8];
        #pragma unroll
        for (int kt = 0; kt < 4; ++kt) {
            half8_t hf;
            #pragma unroll
            for (int e = 0; e < 8; ++e) hf[e] = (_Float16)wr[kt * 32 + e];
            wf[mi][kt] = hf;
        }
    }

    const int batch = g * 16 + n;
    const floatx4 bN = *reinterpret_cast<const floatx4*>(&bhh[256 + w * 16 + q * 4]);
    floatx4 hp = {0.f, 0.f, 0.f, 0.f};

    const int t0 = rev ? (T_SEQ - 1) : 0;
    const int ts = rev ? -1 : 1;

    // dense xp base for this lane: frag f at +f*2048, step t at +t*24576
    const float* xbase = xp + ((size_t)(g * 96 + w * 4 + q) * 16 + n) * 4;

#define XLOAD(S, T)                                                                 \
    do {                                                                            \
        const float* p_ = xbase + (size_t)(T) * 24576;                              \
        S[0] = *reinterpret_cast<const floatx4*>(p_);                               \
        S[1] = *reinterpret_cast<const floatx4*>(p_ + 2048);                        \
        S[2] = *reinterpret_cast<const floatx4*>(p_ + 4096);                        \
    } while (0)

    floatx4 XA[3], XB[3], XC[3], XD[3];
    XLOAD(XA, t0);
    XLOAD(XB, t0 + ts);
    XLOAD(XC, t0 + 2 * ts);

    __syncthreads();   // h-init visible (full drain once)

#define GRU_STEP(RB, WB_, XS, TCUR)                                                 \
    do {                                                                            \
        half8_t bf0 = *reinterpret_cast<const half8_t*>(&hlds[RB][hoff(n, 0 * 32 + q * 8)]); \
        half8_t bf1 = *reinterpret_cast<const half8_t*>(&hlds[RB][hoff(n, 1 * 32 + q * 8)]); \
        half8_t bf2 = *reinterpret_cast<const half8_t*>(&hlds[RB][hoff(n, 2 * 32 + q * 8)]); \
        half8_t bf3 = *reinterpret_cast<const half8_t*>(&hlds[RB][hoff(n, 3 * 32 + q * 8)]); \
        floatx4 a0 = {0.f, 0.f, 0.f, 0.f};                                          \
        floatx4 a1 = {0.f, 0.f, 0.f, 0.f};                                          \
        floatx4 a2 = bN;                                                            \
        a0 = __builtin_amdgcn_mfma_f32_16x16x32_f16(wf[0][0], bf0, a0, 0, 0, 0);    \
        a1 = __builtin_amdgcn_mfma_f32_16x16x32_f16(wf[1][0], bf0, a1, 0, 0, 0);    \
        a2 = __builtin_amdgcn_mfma_f32_16x16x32_f16(wf[2][0], bf0, a2, 0, 0, 0);    \
        a0 = __builtin_amdgcn_mfma_f32_16x16x32_f16(wf[0][1], bf1, a0, 0, 0, 0);    \
        a1 = __builtin_amdgcn_mfma_f32_16x16x32_f16(wf[1][1], bf1, a1, 0, 0, 0);    \
        a2 = __builtin_amdgcn_mfma_f32_16x16x32_f16(wf[2][1], bf1, a2, 0, 0, 0);    \
        a0 = __builtin_amdgcn_mfma_f32_16x16x32_f16(wf[0][2], bf2, a0, 0, 0, 0);    \
        a1 = __builtin_amdgcn_mfma_f32_16x16x32_f16(wf[1][2], bf2, a1, 0, 0, 0);    \
        a2 = __builtin_amdgcn_mfma_f32_16x16x32_f16(wf[2][2], bf2, a2, 0, 0, 0);    \
        a0 = __builtin_amdgcn_mfma_f32_16x16x32_f16(wf[0][3], bf3, a0, 0, 0, 0);    \
        a1 = __builtin_amdgcn_mfma_f32_16x16x32_f16(wf[1][3], bf3, a1, 0, 0, 0);    \
        a2 = __builtin_amdgcn_mfma_f32_16x16x32_f16(wf[2][3], bf3, a2, 0, 0, 0);    \
        floatx4 hnew;                                                               \
        half4_t hh;                                                                 \
        _Pragma("unroll")                                                           \
        for (int rr = 0; rr < 4; ++rr) {                                            \
            const float rg = sigmoid_f(a0[rr] + XS[0][rr]);                         \
            const float zg = sigmoid_f(a1[rr] + XS[1][rr]);                         \
            const float nn = tanh_f(XS[2][rr] + rg * a2[rr]);                       \
            const float hv = fmaf(zg, hp[rr] - nn, nn);                             \
            hnew[rr] = hv;                                                          \
            hh[rr] = (_Float16)hv;                                                  \
        }                                                                           \
        hp = hnew;                                                                  \
        *reinterpret_cast<half4_t*>(&hlds[WB_][hoff(n, w * 16 + q * 4)]) = hh;      \
        if (seqout)                                                                 \
            *reinterpret_cast<floatx4*>(                                            \
                &seqout[((size_t)batch * T_SEQ + (TCUR)) * 256 + dir * 128 +        \
                        w * 16 + q * 4]) = hnew;                                    \
        LDS_BARRIER();                                                              \
    } while (0)

#define CLAMP_T(v) ((v) < 0 ? 0 : ((v) > T_SEQ - 1 ? T_SEQ - 1 : (v)))

    int t = t0;
    for (int it = 0; it < T_SEQ / 4; ++it) {
        { const int tl = CLAMP_T(t + 3 * ts); XLOAD(XD, tl); }
        GRU_STEP(0, 1, XA, t); t += ts;
        { const int tl = CLAMP_T(t + 3 * ts); XLOAD(XA, tl); }
        GRU_STEP(1, 0, XB, t); t += ts;
        { const int tl = CLAMP_T(t + 3 * ts); XLOAD(XB, tl); }
        GRU_STEP(0, 1, XC, t); t += ts;
        { const int tl = CLAMP_T(t + 3 * ts); XLOAD(XC, tl); }
        GRU_STEP(1, 0, XD, t); t += ts;
    }
#undef GRU_STEP
#undef XLOAD
#undef CLAMP_T

    if (hfin)
        *reinterpret_cast<floatx4*>(&hfin[(size_t)batch * 128 + w * 16 + q * 4]) = hp;
}

// ---------- decoder ----------
__device__ __forceinline__ float block_sum128(float v, float* red) {
    #pragma unroll
    for (int o = 32; o > 0; o >>= 1) v += __shfl_down(v, o);
    const int w = threadIdx.x >> 6;
    if ((threadIdx.x & 63) == 0) red[w] = v;
    __syncthreads();
    const float s = red[0] + red[1];
    __syncthreads();
    return s;
}

__global__ __launch_bounds__(128, 1)
void decoder_kernel(const float* __restrict__ hb,
                    const float* __restrict__ g1, const float* __restrict__ be1,
                    const float* __restrict__ W1, const float* __restrict__ b1,
                    const float* __restrict__ g2, const float* __restrict__ be2,
                    const float* __restrict__ W2, const float* __restrict__ b2,
                    float* __restrict__ out)
{
    const int b = blockIdx.x;
    const int j = threadIdx.x;
    __shared__ float buf[H];
    __shared__ float red[2];

    const float m = mish_f(hb[(size_t)b * H + j]);
    const float mean = block_sum128(m, red) * (1.0f / H);
    const float d = m - mean;
    const float var = block_sum128(d * d, red) * (1.0f / H);
    const float y = d * rsqrtf(var + EPS) * g1[j] + be1[j];
    buf[j] = y;
    __syncthreads();

    float acc = b1[j];
    #pragma unroll
    for (int k = 0; k < H; k += 4) {
        const float4 wv = *reinterpret_cast<const float4*>(&W1[(size_t)j * H + k]);
        const float4 yv = *reinterpret_cast<const float4*>(&buf[k]);
        acc += wv.x * yv.x + wv.y * yv.y + wv.z * yv.z + wv.w * yv.w;
    }
    const float m2 = mish_f(acc);
    const float mean2 = block_sum128(m2, red) * (1.0f / H);
    const float d2 = m2 - mean2;
    const float var2 = block_sum128(d2 * d2, red) * (1.0f / H);
    const float y2 = d2 * rsqrtf(var2 + EPS) * g2[j] + be2[j];

    const float p = W2[j] * y2;
    const float s = block_sum128(p, red);
    if (j == 0) out[b] = s + b2[0];
}

// ---------- launch ----------
extern "C" void kernel_launch(void* const* d_in, const int* in_sizes, int n_in,
                              void* d_out, int out_size, void* d_ws, size_t ws_size,
                              hipStream_t stream)
{
    (void)in_sizes; (void)n_in; (void)out_size; (void)ws_size;
    const float* x     = (const float*)d_in[0];
    const float* Wih0f = (const float*)d_in[1];
    const float* Whh0f = (const float*)d_in[2];
    const float* bih0f = (const float*)d_in[3];
    const float* bhh0f = (const float*)d_in[4];
    const float* Wih0b = (const float*)d_in[5];
    const float* Whh0b = (const float*)d_in[6];
    const float* bih0b = (const float*)d_in[7];
    const float* bhh0b = (const float*)d_in[8];
    // d_in[9..12] = layer-1 forward params: unused (hf discarded by reference)
    const float* Wih1b = (const float*)d_in[13];
    const float* Whh1b = (const float*)d_in[14];
    const float* bih1b = (const float*)d_in[15];
    const float* bhh1b = (const float*)d_in[16];
    const float* g1  = (const float*)d_in[17];
    const float* be1 = (const float*)d_in[18];
    const float* W1  = (const float*)d_in[19];
    const float* b1  = (const float*)d_in[20];
    const float* g2  = (const float*)d_in[21];
    const float* be2 = (const float*)d_in[22];
    const float* W2  = (const float*)d_in[23];
    const float* b2  = (const float*)d_in[24];
    float* out = (float*)d_out;

    float* ws = (float*)d_ws;
    const size_t XP_ELEMS = (size_t)T_SEQ * BATCH * 384;
    const size_t X1_ELEMS = (size_t)BATCH * T_SEQ * 256;
    float* xp0f = ws;
    float* xp0b = xp0f + XP_ELEMS;
    float* x1   = xp0b + XP_ELEMS;
    float* hbuf = x1 + X1_ELEMS;
    float* xp1b = xp0f;   // xp0f dead after layer-0 scan

    const dim3 pgrid(3, 1024);
    proj_kernel<512><<<pgrid, 256, 0, stream>>>(x, Wih0f, bih0f, bhh0f, xp0f);
    proj_kernel<512><<<pgrid, 256, 0, stream>>>(x, Wih0b, bih0b, bhh0b, xp0b);
    gru_scan8<<<dim3(8), 512, 0, stream>>>(xp0f, xp0b, Whh0f, Whh0b, bhh0f, bhh0b,
                                           0, 1, x1, nullptr);
    proj_kernel<256><<<pgrid, 256, 0, stream>>>(x1, Wih1b, bih1b, bhh1b, xp1b);
    gru_scan8<<<dim3(4), 512, 0, stream>>>(xp1b, xp1b, Whh1b, Whh1b, bhh1b, bhh1b,
                                           1, 1, nullptr, hbuf);
    decoder_kernel<<<64, 128, 0, stream>>>(hbuf, g1, be1, W1, b1, g2, be2, W2, b2, out);
}

// Round 9
// 3935.925 us; speedup vs baseline: 2.4137x; 1.2439x over previous
//
#include <hip/hip_runtime.h>
#include <hip/hip_bf16.h>
#include <cstddef>

#define T_SEQ 2048
#define BATCH 64
#define H 128
#define EPS 1e-5f

typedef _Float16 half8_t __attribute__((ext_vector_type(8)));
typedef _Float16 half4_t __attribute__((ext_vector_type(4)));
typedef float floatx4 __attribute__((ext_vector_type(4)));

// ---------- math helpers ----------
__device__ __forceinline__ float sigmoid_f(float x) {
    return __builtin_amdgcn_rcpf(1.0f + __expf(-x));   // rcp(inf)=0 saturates
}
__device__ __forceinline__ float tanh_f(float x) {
    return fmaf(2.0f, __builtin_amdgcn_rcpf(1.0f + __expf(-2.0f * x)), -1.0f);
}
__device__ __forceinline__ float mish_f(float x) {
    float sp = (x > 15.0f) ? x : log1pf(__expf(x));
    return x * tanh_f(sp);
}

// ---------- xp layout ----------
// XP[t][g][cq][n][c] : t in [0,2048), g = b>>4, cq = col>>2 (col in [0,384)),
// n = b&15, c = col&3. Flat = (((t*4+g)*96 + cq)*16 + n)*4 + c.
// Scan wave's per-fragment load is 1024B contiguous; step = dense 24KB block.

// ---------- input-projection GEMM, fp16 MFMA ----------
// xp[t,b,col] = A[(b*T+t)][:K] . W[col][:K] + bih[col] + (col<256 ? bhh[col] : 0)
// A-operand = W rows (gate cols n), B-operand = x rows (m = t*64+b)  ->
// D: col(lane&15) = m-slot, row((lane>>4)*4+rr) = n  (same verified mapping
// as the scan). 128x128 tile, BK=32, 4 waves (64x64 each), double-buffered
// LDS [128][40] fp16 (80B row stride -> 2-way bank aliasing = free),
// issue-early/write-late staging with fp32->fp16 convert in registers.
template<int K>
__global__ __launch_bounds__(256, 2)
void proj_mfma(const float* __restrict__ A, const float* __restrict__ W,
               const float* __restrict__ bih, const float* __restrict__ bhh,
               float* __restrict__ C)
{
    constexpr int NKT = K / 32;
    __shared__ _Float16 Ws[2][128][40];
    __shared__ _Float16 Xs[2][128][40];

    const int tid = threadIdx.x;
    const int w = tid >> 6, l = tid & 63;
    const int lm = l & 15, q = l >> 4;
    const int wm = (w & 1) * 64, wn = (w >> 1) * 64;
    const int n0 = blockIdx.x * 128;
    const int m0 = blockIdx.y * 128;

    // staging coords: thread -> (row sr, k-half sk)
    const int sr = tid >> 1;
    const int sk = (tid & 1) * 16;
    const int sm = m0 + sr;
    const float* xrow = A + ((size_t)(sm & 63) * T_SEQ + (sm >> 6)) * K + sk;
    const float* wrow = W + (size_t)(n0 + sr) * K + sk;

    floatx4 acc[4][4];
    #pragma unroll
    for (int i = 0; i < 4; ++i)
        #pragma unroll
        for (int j = 0; j < 4; ++j) acc[i][j] = floatx4{0.f, 0.f, 0.f, 0.f};

    floatx4 bv[4];
    #pragma unroll
    for (int nf = 0; nf < 4; ++nf) {
        const int nc = n0 + wn + nf * 16 + q * 4;
        floatx4 b = *reinterpret_cast<const floatx4*>(&bih[nc]);
        if (nc < 256) b += *reinterpret_cast<const floatx4*>(&bhh[nc]);
        bv[nf] = b;
    }

    floatx4 lx[4], lw[4];

#define STORE_STAGE(B)                                                          \
    do {                                                                        \
        half8_t h0, h1, g0, g1;                                                 \
        _Pragma("unroll")                                                       \
        for (int e = 0; e < 4; ++e) {                                           \
            h0[e] = (_Float16)lx[0][e]; h0[4 + e] = (_Float16)lx[1][e];         \
            h1[e] = (_Float16)lx[2][e]; h1[4 + e] = (_Float16)lx[3][e];         \
            g0[e] = (_Float16)lw[0][e]; g0[4 + e] = (_Float16)lw[1][e];         \
            g1[e] = (_Float16)lw[2][e]; g1[4 + e] = (_Float16)lw[3][e];         \
        }                                                                       \
        *reinterpret_cast<half8_t*>(&Xs[B][sr][sk])     = h0;                   \
        *reinterpret_cast<half8_t*>(&Xs[B][sr][sk + 8]) = h1;                   \
        *reinterpret_cast<half8_t*>(&Ws[B][sr][sk])     = g0;                   \
        *reinterpret_cast<half8_t*>(&Ws[B][sr][sk + 8]) = g1;                   \
    } while (0)

    // prologue: stage k-tile 0
    #pragma unroll
    for (int i = 0; i < 4; ++i) {
        lx[i] = *reinterpret_cast<const floatx4*>(xrow + i * 4);
        lw[i] = *reinterpret_cast<const floatx4*>(wrow + i * 4);
    }
    STORE_STAGE(0);
    __syncthreads();

    int buf = 0;
    for (int kt = 0; kt < NKT; ++kt) {
        if (kt + 1 < NKT) {   // issue next-tile loads early (hide under MFMA)
            #pragma unroll
            for (int i = 0; i < 4; ++i) {
                lx[i] = *reinterpret_cast<const floatx4*>(xrow + (kt + 1) * 32 + i * 4);
                lw[i] = *reinterpret_cast<const floatx4*>(wrow + (kt + 1) * 32 + i * 4);
            }
        }
        half8_t af[4], bf[4];
        #pragma unroll
        for (int f = 0; f < 4; ++f) {
            af[f] = *reinterpret_cast<const half8_t*>(&Ws[buf][wn + f * 16 + lm][q * 8]);
            bf[f] = *reinterpret_cast<const half8_t*>(&Xs[buf][wm + f * 16 + lm][q * 8]);
        }
        #pragma unroll
        for (int nf = 0; nf < 4; ++nf)
            #pragma unroll
            for (int mf = 0; mf < 4; ++mf)
                acc[nf][mf] = __builtin_amdgcn_mfma_f32_16x16x32_f16(
                    af[nf], bf[mf], acc[nf][mf], 0, 0, 0);
        if (kt + 1 < NKT) STORE_STAGE(buf ^ 1);
        __syncthreads();
        buf ^= 1;
    }
#undef STORE_STAGE

    // epilogue: bias + store in XP layout (16-lane-contiguous 256B blocks)
    #pragma unroll
    for (int nf = 0; nf < 4; ++nf) {
        const int nc = n0 + wn + nf * 16 + q * 4;
        const int cq = nc >> 2;
        #pragma unroll
        for (int mf = 0; mf < 4; ++mf) {
            const int m = m0 + wm + mf * 16 + lm;
            const int t = m >> 6, g = (m >> 4) & 3, nb = m & 15;
            const floatx4 o = acc[nf][mf] + bv[nf];
            *reinterpret_cast<floatx4*>(
                &C[(((size_t)t * 4 + g) * 96 + cq) * 64 + nb * 4]) = o;
        }
    }
}

// ---------- MFMA GRU scan v5 (validated r8: 1672 us) ----------
__device__ __forceinline__ int hoff(int n, int k) {
    return (n * 256 + k * 2) ^ ((n & 7) << 4);
}
#define LDS_BARRIER() asm volatile("s_waitcnt lgkmcnt(0)\n\ts_barrier" ::: "memory")

__global__ __launch_bounds__(512, 2)
void gru_scan8(const float* __restrict__ xpA, const float* __restrict__ xpB,
               const float* __restrict__ WA, const float* __restrict__ WB,
               const float* __restrict__ bA, const float* __restrict__ bB,
               int revA, int revB,
               float* __restrict__ seqout,   // x1 [B][T][256] or nullptr
               float* __restrict__ hfin)     // [B][H] or nullptr
{
    const int tid = threadIdx.x;
    const int w = tid >> 6;        // wave 0..7
    const int l = tid & 63;
    const int n = l & 15;          // batch slot
    const int q = l >> 4;          // lane quarter

    const int cid = blockIdx.x;
    const int dir = cid >> 2;
    const int g = cid & 3;

    const float* __restrict__ xp  = dir ? xpB : xpA;
    const float* __restrict__ Whh = dir ? WB : WA;
    const float* __restrict__ bhh = dir ? bB : bA;
    const int rev = dir ? revB : revA;

    __shared__ __align__(16) unsigned char hlds[2][4096];

    *reinterpret_cast<unsigned long long*>(&hlds[0][tid * 8]) = 0ull;

    half8_t wf[3][4];
    #pragma unroll
    for (int mi = 0; mi < 3; ++mi) {
        const float* wr = &Whh[(size_t)((mi * 8 + w) * 16 + n) * 128 + q * 8];
        #pragma unroll
        for (int kt = 0; kt < 4; ++kt) {
            half8_t hf;
            #pragma unroll
            for (int e = 0; e < 8; ++e) hf[e] = (_Float16)wr[kt * 32 + e];
            wf[mi][kt] = hf;
        }
    }

    const int batch = g * 16 + n;
    const floatx4 bN = *reinterpret_cast<const floatx4*>(&bhh[256 + w * 16 + q * 4]);
    floatx4 hp = {0.f, 0.f, 0.f, 0.f};

    const int t0 = rev ? (T_SEQ - 1) : 0;
    const int ts = rev ? -1 : 1;

    const float* xbase = xp + ((size_t)(g * 96 + w * 4 + q) * 16 + n) * 4;

#define XLOAD(S, T)                                                                 \
    do {                                                                            \
        const float* p_ = xbase + (size_t)(T) * 24576;                              \
        S[0] = *reinterpret_cast<const floatx4*>(p_);                               \
        S[1] = *reinterpret_cast<const floatx4*>(p_ + 2048);                        \
        S[2] = *reinterpret_cast<const floatx4*>(p_ + 4096);                        \
    } while (0)

    floatx4 XA[3], XB[3], XC[3], XD[3];
    XLOAD(XA, t0);
    XLOAD(XB, t0 + ts);
    XLOAD(XC, t0 + 2 * ts);

    __syncthreads();

#define GRU_STEP(RB, WB_, XS, TCUR)                                                 \
    do {                                                                            \
        half8_t bf0 = *reinterpret_cast<const half8_t*>(&hlds[RB][hoff(n, 0 * 32 + q * 8)]); \
        half8_t bf1 = *reinterpret_cast<const half8_t*>(&hlds[RB][hoff(n, 1 * 32 + q * 8)]); \
        half8_t bf2 = *reinterpret_cast<const half8_t*>(&hlds[RB][hoff(n, 2 * 32 + q * 8)]); \
        half8_t bf3 = *reinterpret_cast<const half8_t*>(&hlds[RB][hoff(n, 3 * 32 + q * 8)]); \
        floatx4 a0 = {0.f, 0.f, 0.f, 0.f};                                          \
        floatx4 a1 = {0.f, 0.f, 0.f, 0.f};                                          \
        floatx4 a2 = bN;                                                            \
        a0 = __builtin_amdgcn_mfma_f32_16x16x32_f16(wf[0][0], bf0, a0, 0, 0, 0);    \
        a1 = __builtin_amdgcn_mfma_f32_16x16x32_f16(wf[1][0], bf0, a1, 0, 0, 0);    \
        a2 = __builtin_amdgcn_mfma_f32_16x16x32_f16(wf[2][0], bf0, a2, 0, 0, 0);    \
        a0 = __builtin_amdgcn_mfma_f32_16x16x32_f16(wf[0][1], bf1, a0, 0, 0, 0);    \
        a1 = __builtin_amdgcn_mfma_f32_16x16x32_f16(wf[1][1], bf1, a1, 0, 0, 0);    \
        a2 = __builtin_amdgcn_mfma_f32_16x16x32_f16(wf[2][1], bf1, a2, 0, 0, 0);    \
        a0 = __builtin_amdgcn_mfma_f32_16x16x32_f16(wf[0][2], bf2, a0, 0, 0, 0);    \
        a1 = __builtin_amdgcn_mfma_f32_16x16x32_f16(wf[1][2], bf2, a1, 0, 0, 0);    \
        a2 = __builtin_amdgcn_mfma_f32_16x16x32_f16(wf[2][2], bf2, a2, 0, 0, 0);    \
        a0 = __builtin_amdgcn_mfma_f32_16x16x32_f16(wf[0][3], bf3, a0, 0, 0, 0);    \
        a1 = __builtin_amdgcn_mfma_f32_16x16x32_f16(wf[1][3], bf3, a1, 0, 0, 0);    \
        a2 = __builtin_amdgcn_mfma_f32_16x16x32_f16(wf[2][3], bf3, a2, 0, 0, 0);    \
        floatx4 hnew;                                                               \
        half4_t hh;                                                                 \
        _Pragma("unroll")                                                           \
        for (int rr = 0; rr < 4; ++rr) {                                            \
            const float rg = sigmoid_f(a0[rr] + XS[0][rr]);                         \
            const float zg = sigmoid_f(a1[rr] + XS[1][rr]);                         \
            const float nn = tanh_f(XS[2][rr] + rg * a2[rr]);                       \
            const float hv = fmaf(zg, hp[rr] - nn, nn);                             \
            hnew[rr] = hv;                                                          \
            hh[rr] = (_Float16)hv;                                                  \
        }                                                                           \
        hp = hnew;                                                                  \
        *reinterpret_cast<half4_t*>(&hlds[WB_][hoff(n, w * 16 + q * 4)]) = hh;      \
        if (seqout)                                                                 \
            *reinterpret_cast<floatx4*>(                                            \
                &seqout[((size_t)batch * T_SEQ + (TCUR)) * 256 + dir * 128 +        \
                        w * 16 + q * 4]) = hnew;                                    \
        LDS_BARRIER();                                                              \
    } while (0)

#define CLAMP_T(v) ((v) < 0 ? 0 : ((v) > T_SEQ - 1 ? T_SEQ - 1 : (v)))

    int t = t0;
    for (int it = 0; it < T_SEQ / 4; ++it) {
        { const int tl = CLAMP_T(t + 3 * ts); XLOAD(XD, tl); }
        GRU_STEP(0, 1, XA, t); t += ts;
        { const int tl = CLAMP_T(t + 3 * ts); XLOAD(XA, tl); }
        GRU_STEP(1, 0, XB, t); t += ts;
        { const int tl = CLAMP_T(t + 3 * ts); XLOAD(XB, tl); }
        GRU_STEP(0, 1, XC, t); t += ts;
        { const int tl = CLAMP_T(t + 3 * ts); XLOAD(XC, tl); }
        GRU_STEP(1, 0, XD, t); t += ts;
    }
#undef GRU_STEP
#undef XLOAD
#undef CLAMP_T

    if (hfin)
        *reinterpret_cast<floatx4*>(&hfin[(size_t)batch * 128 + w * 16 + q * 4]) = hp;
}

// ---------- decoder ----------
__device__ __forceinline__ float block_sum128(float v, float* red) {
    #pragma unroll
    for (int o = 32; o > 0; o >>= 1) v += __shfl_down(v, o);
    const int w = threadIdx.x >> 6;
    if ((threadIdx.x & 63) == 0) red[w] = v;
    __syncthreads();
    const float s = red[0] + red[1];
    __syncthreads();
    return s;
}

__global__ __launch_bounds__(128, 1)
void decoder_kernel(const float* __restrict__ hb,
                    const float* __restrict__ g1, const float* __restrict__ be1,
                    const float* __restrict__ W1, const float* __restrict__ b1,
                    const float* __restrict__ g2, const float* __restrict__ be2,
                    const float* __restrict__ W2, const float* __restrict__ b2,
                    float* __restrict__ out)
{
    const int b = blockIdx.x;
    const int j = threadIdx.x;
    __shared__ float buf[H];
    __shared__ float red[2];

    const float m = mish_f(hb[(size_t)b * H + j]);
    const float mean = block_sum128(m, red) * (1.0f / H);
    const float d = m - mean;
    const float var = block_sum128(d * d, red) * (1.0f / H);
    const float y = d * rsqrtf(var + EPS) * g1[j] + be1[j];
    buf[j] = y;
    __syncthreads();

    float acc = b1[j];
    #pragma unroll
    for (int k = 0; k < H; k += 4) {
        const float4 wv = *reinterpret_cast<const float4*>(&W1[(size_t)j * H + k]);
        const float4 yv = *reinterpret_cast<const float4*>(&buf[k]);
        acc += wv.x * yv.x + wv.y * yv.y + wv.z * yv.z + wv.w * yv.w;
    }
    const float m2 = mish_f(acc);
    const float mean2 = block_sum128(m2, red) * (1.0f / H);
    const float d2 = m2 - mean2;
    const float var2 = block_sum128(d2 * d2, red) * (1.0f / H);
    const float y2 = d2 * rsqrtf(var2 + EPS) * g2[j] + be2[j];

    const float p = W2[j] * y2;
    const float s = block_sum128(p, red);
    if (j == 0) out[b] = s + b2[0];
}

// ---------- launch ----------
extern "C" void kernel_launch(void* const* d_in, const int* in_sizes, int n_in,
                              void* d_out, int out_size, void* d_ws, size_t ws_size,
                              hipStream_t stream)
{
    (void)in_sizes; (void)n_in; (void)out_size; (void)ws_size;
    const float* x     = (const float*)d_in[0];
    const float* Wih0f = (const float*)d_in[1];
    const float* Whh0f = (const float*)d_in[2];
    const float* bih0f = (const float*)d_in[3];
    const float* bhh0f = (const float*)d_in[4];
    const float* Wih0b = (const float*)d_in[5];
    const float* Whh0b = (const float*)d_in[6];
    const float* bih0b = (const float*)d_in[7];
    const float* bhh0b = (const float*)d_in[8];
    // d_in[9..12] = layer-1 forward params: unused (hf discarded by reference)
    const float* Wih1b = (const float*)d_in[13];
    const float* Whh1b = (const float*)d_in[14];
    const float* bih1b = (const float*)d_in[15];
    const float* bhh1b = (const float*)d_in[16];
    const float* g1  = (const float*)d_in[17];
    const float* be1 = (const float*)d_in[18];
    const float* W1  = (const float*)d_in[19];
    const float* b1  = (const float*)d_in[20];
    const float* g2  = (const float*)d_in[21];
    const float* be2 = (const float*)d_in[22];
    const float* W2  = (const float*)d_in[23];
    const float* b2  = (const float*)d_in[24];
    float* out = (float*)d_out;

    float* ws = (float*)d_ws;
    const size_t XP_ELEMS = (size_t)T_SEQ * BATCH * 384;
    const size_t X1_ELEMS = (size_t)BATCH * T_SEQ * 256;
    float* xp0f = ws;
    float* xp0b = xp0f + XP_ELEMS;
    float* x1   = xp0b + XP_ELEMS;
    float* hbuf = x1 + X1_ELEMS;
    float* xp1b = xp0f;   // xp0f dead after layer-0 scan

    const dim3 pgrid(3, 1024);
    proj_mfma<512><<<pgrid, 256, 0, stream>>>(x, Wih0f, bih0f, bhh0f, xp0f);
    proj_mfma<512><<<pgrid, 256, 0, stream>>>(x, Wih0b, bih0b, bhh0b, xp0b);
    gru_scan8<<<dim3(8), 512, 0, stream>>>(xp0f, xp0b, Whh0f, Whh0b, bhh0f, bhh0b,
                                           0, 1, x1, nullptr);
    proj_mfma<256><<<pgrid, 256, 0, stream>>>(x1, Wih1b, bih1b, bhh1b, xp1b);
    gru_scan8<<<dim3(4), 512, 0, stream>>>(xp1b, xp1b, Whh1b, Whh1b, bhh1b, bhh1b,
                                           1, 1, nullptr, hbuf);
    decoder_kernel<<<64, 128, 0, stream>>>(hbuf, g1, be1, W1, b1, g2, be2, W2, b2, out);
}